// Round 4
// baseline (321.665 us; speedup 1.0000x reference)
//
#include <hip/hip_runtime.h>

// (B,N,D,K) = (32, 2048, 512, 256)
#define CB 32
#define CN 2048
#define CD 512
#define CK 256

typedef __bf16 bf16x8 __attribute__((ext_vector_type(8)));
typedef float  f32x4  __attribute__((ext_vector_type(4)));

__device__ __forceinline__ unsigned pk2bf(float a, float b) {   // RNE pack: 2 f32 -> bf16x2
    union { float f; unsigned u; } x, y; x.f = a; y.f = b;
    unsigned ru = x.u + 0x7fffu + ((x.u >> 16) & 1u);
    unsigned rv = y.u + 0x7fffu + ((y.u >> 16) & 1u);
    return (ru >> 16) | (rv & 0xffff0000u);
}

// ---------------- K0: vQp (blocks 0..31) + WiT (blocks 32..287) ----------------
__global__ __launch_bounds__(256) void prep_kernel(
        const float* __restrict__ vQ, const float* __restrict__ Wq,
        const float* __restrict__ bq, const float* __restrict__ Wi,
        float* __restrict__ vQp, unsigned short* __restrict__ WiT)
{
    const int tid = threadIdx.x;
    if (blockIdx.x < CB) {
        const int b = blockIdx.x;
        __shared__ float sq[CD];
        sq[tid]       = vQ[b * CD + tid];
        sq[tid + 256] = vQ[b * CD + tid + 256];
        __syncthreads();
        float acc = bq[tid];
        #pragma unroll 8
        for (int d = 0; d < CD; ++d) acc += sq[d] * Wq[d * CK + tid];
        vQp[b * CK + tid] = acc;
    } else {
        const int k = blockIdx.x - CB;
        for (int d = tid; d < CD; d += 256) {
            union { float f; unsigned u; } x; x.f = Wi[(size_t)d * CK + k];
            unsigned r = x.u + 0x7fffu + ((x.u >> 16) & 1u);
            WiT[(size_t)k * CD + d] = (unsigned short)(r >> 16);
        }
    }
}

// ---------------- K1: fused scores + softmax pieces + num, single vI pass ----------
// BM=64; A resident in LDS (64x512 bf16, 16B-chunk xor-swizzled, 64 KB);
// B [256][32] bf16 (16 KB) reg-double-buffered. 80 KB total -> 2 blocks/CU.
__global__ __launch_bounds__(256, 2) void scores_fused_kernel(
        const float* __restrict__ vI, const unsigned short* __restrict__ WiT,
        const float* __restrict__ vQp, const float* __restrict__ Wp,
        float* __restrict__ numP, float* __restrict__ Zp, float* __restrict__ mP)
{
    constexpr int BM = 64;
    __shared__ __align__(16) unsigned short sA[BM * CD];   // 65536 B
    __shared__ __align__(16) unsigned short sB[CK * 32];   // 16384 B
    float* sred = (float*)sB;          // [4][64]   (aliased post-K-loop)
    float* sS   = ((float*)sB) + 256;  // [64] scores
    float* sW   = ((float*)sB) + 320;  // [64] exp weights
    float* sacc = ((float*)sB) + 512;  // [4][512] num partials

    const int tid  = threadIdx.x;
    const int b    = blockIdx.y;
    const int n0   = blockIdx.x * BM;
    const int wave = tid >> 6;
    const int lane = tid & 63;
    const int col  = lane & 15;
    const int quad = lane >> 4;
    const float* vIb = vI + ((size_t)b * CN + n0) * CD;

    // ---- B prefetch (registers): thread covers rows tid/4 + j*64, 16B each ----
    const unsigned short* wB = WiT + (size_t)(tid >> 2) * CD + (tid & 3) * 8;
    uint4 rb[2][4];
    #pragma unroll
    for (int j = 0; j < 4; ++j)
        rb[0][j] = *reinterpret_cast<const uint4*>(wB + (size_t)j * 64 * CD);
    #pragma unroll
    for (int j = 0; j < 4; ++j)
        rb[1][j] = *reinterpret_cast<const uint4*>(wB + (size_t)j * 64 * CD + 32);

    // ---- stage ALL of A: 64x512 f32 -> bf16, swizzled 16B chunks ----
    #pragma unroll
    for (int i = 0; i < 16; ++i) {
        int q = i * 256 + tid;           // chunk id over 64x64
        int r = q >> 6, c = q & 63;
        const float* src = vIb + (size_t)r * CD + c * 8;
        float4 v0 = *reinterpret_cast<const float4*>(src);
        float4 v1 = *reinterpret_cast<const float4*>(src + 4);
        uint4 p;
        p.x = pk2bf(v0.x, v0.y); p.y = pk2bf(v0.z, v0.w);
        p.z = pk2bf(v1.x, v1.y); p.w = pk2bf(v1.z, v1.w);
        *reinterpret_cast<uint4*>(&sA[r * CD + ((c ^ (r & 7)) << 3)]) = p;
    }

    f32x4 acc[4][4];
    #pragma unroll
    for (int mt = 0; mt < 4; ++mt)
        #pragma unroll
        for (int kt = 0; kt < 4; ++kt)
            acc[mt][kt] = (f32x4){0.f, 0.f, 0.f, 0.f};

    // write B chunk 0 (loads long drained by A-stage)
    #pragma unroll
    for (int j = 0; j < 4; ++j)
        *reinterpret_cast<uint4*>(&sB[tid * 8 + j * 2048]) = rb[0][j];
    __syncthreads();

    // ---- K loop: 16 chunks of 32 d ----
    #pragma unroll
    for (int ch = 0; ch < 16; ++ch) {
        bf16x8 af[4], bfr[4];
        #pragma unroll
        for (int mt = 0; mt < 4; ++mt) {
            int row = mt * 16 + col;
            int c   = ch * 4 + quad;
            af[mt] = *reinterpret_cast<const bf16x8*>(
                &sA[row * CD + ((c ^ (row & 7)) << 3)]);
        }
        #pragma unroll
        for (int kt = 0; kt < 4; ++kt) {
            int R = wave * 64 + kt * 16 + col;
            bfr[kt] = *reinterpret_cast<const bf16x8*>(&sB[R * 32 + quad * 8]);
        }
        #pragma unroll
        for (int mt = 0; mt < 4; ++mt)
            #pragma unroll
            for (int kt = 0; kt < 4; ++kt)
                acc[mt][kt] = __builtin_amdgcn_mfma_f32_16x16x32_bf16(
                    af[mt], bfr[kt], acc[mt][kt], 0, 0, 0);
        __syncthreads();                 // all sB reads done
        if (ch < 15) {
            const int sel = 1 - (ch & 1);    // buffer holding chunk ch+1
            #pragma unroll
            for (int j = 0; j < 4; ++j)
                *reinterpret_cast<uint4*>(&sB[tid * 8 + j * 2048]) = rb[sel][j];
            if (ch < 14) {                   // prefetch chunk ch+2 into same buffer
                const int d0n = (ch + 2) * 32;
                #pragma unroll
                for (int j = 0; j < 4; ++j)
                    rb[sel][j] = *reinterpret_cast<const uint4*>(
                        wB + (size_t)j * 64 * CD + d0n);
            }
            __syncthreads();             // new chunk visible
        }
    }

    // ---- epilogue 1: per-row scores ----
    float vq[4], wp[4];
    #pragma unroll
    for (int kt = 0; kt < 4; ++kt) {
        int k = wave * 64 + kt * 16 + col;
        vq[kt] = vQp[b * CK + k];
        wp[kt] = Wp[k];
    }
    float sp[4][4];
    #pragma unroll
    for (int mt = 0; mt < 4; ++mt)
        #pragma unroll
        for (int r = 0; r < 4; ++r) {
            float s = 0.f;
            #pragma unroll
            for (int kt = 0; kt < 4; ++kt) {
                float v = acc[mt][kt][r] + vq[kt];
                v = v > 0.f ? v : 0.01f * v;     // leaky relu
                s += v * wp[kt];
            }
            sp[mt][r] = s;
        }
    #pragma unroll
    for (int off = 1; off < 16; off <<= 1)
        #pragma unroll
        for (int mt = 0; mt < 4; ++mt)
            #pragma unroll
            for (int r = 0; r < 4; ++r)
                sp[mt][r] += __shfl_xor(sp[mt][r], off);
    if (col == 0) {
        #pragma unroll
        for (int mt = 0; mt < 4; ++mt)
            #pragma unroll
            for (int r = 0; r < 4; ++r)
                sred[wave * 64 + mt * 16 + quad * 4 + r] = sp[mt][r];
    }
    __syncthreads();
    if (tid < BM)
        sS[tid] = sred[tid] + sred[64 + tid] + sred[128 + tid] + sred[192 + tid];
    __syncthreads();

    // ---- epilogue 2: block-local softmax pieces ----
    float m = -1e30f;
    #pragma unroll 8
    for (int i = 0; i < BM; ++i) m = fmaxf(m, sS[i]);
    if (tid < BM) sW[tid] = __expf(sS[tid] - m);
    __syncthreads();
    const int pidx = b * 32 + blockIdx.x;
    if (tid < 64) {
        float z = sW[tid];
        #pragma unroll
        for (int off = 32; off > 0; off >>= 1) z += __shfl_xor(z, off);
        if (tid == 0) { Zp[pidx] = z; mP[pidx] = m; }
    }

    // ---- epilogue 3: num[d] = sum_n w_n * A_lds[n][d] (no global re-read) ----
    float a8[8] = {0.f, 0.f, 0.f, 0.f, 0.f, 0.f, 0.f, 0.f};
    #pragma unroll
    for (int i = 0; i < 16; ++i) {
        int n = wave * 16 + i;
        float w = sW[n];
        uint4 q = *reinterpret_cast<const uint4*>(&sA[n * CD + ((lane ^ (n & 7)) << 3)]);
        a8[0] += w * __uint_as_float(q.x << 16);
        a8[1] += w * __uint_as_float(q.x & 0xffff0000u);
        a8[2] += w * __uint_as_float(q.y << 16);
        a8[3] += w * __uint_as_float(q.y & 0xffff0000u);
        a8[4] += w * __uint_as_float(q.z << 16);
        a8[5] += w * __uint_as_float(q.z & 0xffff0000u);
        a8[6] += w * __uint_as_float(q.w << 16);
        a8[7] += w * __uint_as_float(q.w & 0xffff0000u);
    }
    __syncthreads();   // sW reads done before sacc (same alias region) is written
    *reinterpret_cast<float4*>(&sacc[wave * 512 + lane * 8])     = (float4){a8[0], a8[1], a8[2], a8[3]};
    *reinterpret_cast<float4*>(&sacc[wave * 512 + lane * 8 + 4]) = (float4){a8[4], a8[5], a8[6], a8[7]};
    __syncthreads();
    #pragma unroll
    for (int c = tid; c < CD; c += 256)
        numP[(size_t)pidx * CD + c] =
            sacc[c] + sacc[512 + c] + sacc[1024 + c] + sacc[1536 + c];
}

// ---------------- K2: combine 32 partials -> vbar; out = vbar@Wi + vQp ----------------
__global__ __launch_bounds__(256) void finalize_kernel(
        const float* __restrict__ numP, const float* __restrict__ Zp,
        const float* __restrict__ mP, const float* __restrict__ Wi,
        const float* __restrict__ vQp, float* __restrict__ out)
{
    const int b = blockIdx.x, tid = threadIdx.x;
    __shared__ float sv[CD];
    float M = -1e30f;
    #pragma unroll
    for (int j = 0; j < 32; ++j) M = fmaxf(M, mP[b * 32 + j]);
    float w[32]; float Zt = 0.f;
    #pragma unroll
    for (int j = 0; j < 32; ++j) {
        w[j] = __expf(mP[b * 32 + j] - M);
        Zt += w[j] * Zp[b * 32 + j];
    }
    const float inv = 1.f / Zt;
    for (int c = tid; c < CD; c += 256) {
        float s = 0.f;
        #pragma unroll
        for (int j = 0; j < 32; ++j) s += w[j] * numP[(size_t)(b * 32 + j) * CD + c];
        sv[c] = s * inv;
    }
    __syncthreads();
    float acc = vQp[b * CK + tid];
    #pragma unroll 8
    for (int d = 0; d < CD; ++d) acc += sv[d] * Wi[d * CK + tid];
    out[b * CK + tid] = acc;
}

extern "C" void kernel_launch(void* const* d_in, const int* in_sizes, int n_in,
                              void* d_out, int out_size, void* d_ws, size_t ws_size,
                              hipStream_t stream)
{
    const float* vI = (const float*)d_in[0];   // [B,N,D]
    const float* vQ = (const float*)d_in[1];   // [B,D]
    const float* Wi = (const float*)d_in[2];   // [D,K]
    const float* Wq = (const float*)d_in[3];   // [D,K]
    const float* bq = (const float*)d_in[4];   // [K]
    const float* Wp = (const float*)d_in[5];   // [K,1]
    // d_in[6] = bp: softmax-invariant, unused
    float* out = (float*)d_out;                // [B,K]

    char* ws = (char*)d_ws;
    float*          vQp  = (float*)(ws);                         //  32 KB
    unsigned short* WiT  = (unsigned short*)(ws + 32768);        // 256 KB
    float*          numP = (float*)(ws + 294912);                //   2 MB
    float*          Zp   = (float*)(ws + 294912 + 2097152);      //   4 KB
    float*          mP   = (float*)(ws + 294912 + 2097152 + 4096);

    prep_kernel        <<<CB + CK, 256, 0, stream>>>(vQ, Wq, bq, Wi, vQp, WiT);
    scores_fused_kernel<<<dim3(CN / 64, CB), 256, 0, stream>>>(vI, WiT, vQp, Wp,
                                                               numP, Zp, mP);
    finalize_kernel    <<<CB, 256, 0, stream>>>(numP, Zp, mP, Wi, vQp, out);
}

// Round 5
// 278.711 us; speedup vs baseline: 1.1541x; 1.1541x over previous
//
#include <hip/hip_runtime.h>

// (B,N,D,K) = (32, 2048, 512, 256)
#define CB 32
#define CN 2048
#define CD 512
#define CK 256

typedef __bf16 bf16x8 __attribute__((ext_vector_type(8)));
typedef float  f32x4  __attribute__((ext_vector_type(4)));

__device__ __forceinline__ unsigned pk2bf(float a, float b) {   // RNE pack: 2 f32 -> bf16x2
    union { float f; unsigned u; } x, y; x.f = a; y.f = b;
    unsigned ru = x.u + 0x7fffu + ((x.u >> 16) & 1u);
    unsigned rv = y.u + 0x7fffu + ((y.u >> 16) & 1u);
    return (ru >> 16) | (rv & 0xffff0000u);
}

__device__ __forceinline__ void glds16(const void* g, void* l) {
    __builtin_amdgcn_global_load_lds(
        (const __attribute__((address_space(1))) void*)g,
        (__attribute__((address_space(3))) void*)l, 16, 0, 0);
}

// ---------------- K0: vQp (blocks 0..31) + WiT (blocks 32..287) ----------------
__global__ __launch_bounds__(256) void prep_kernel(
        const float* __restrict__ vQ, const float* __restrict__ Wq,
        const float* __restrict__ bq, const float* __restrict__ Wi,
        float* __restrict__ vQp, unsigned short* __restrict__ WiT)
{
    const int tid = threadIdx.x;
    if (blockIdx.x < CB) {
        const int b = blockIdx.x;
        __shared__ float sq[CD];
        sq[tid]       = vQ[b * CD + tid];
        sq[tid + 256] = vQ[b * CD + tid + 256];
        __syncthreads();
        float acc = bq[tid];
        #pragma unroll 8
        for (int d = 0; d < CD; ++d) acc += sq[d] * Wq[d * CK + tid];
        vQp[b * CK + tid] = acc;
    } else {
        const int k = blockIdx.x - CB;
        for (int d = tid; d < CD; d += 256) {
            union { float f; unsigned u; } x; x.f = Wi[(size_t)d * CK + k];
            unsigned r = x.u + 0x7fffu + ((x.u >> 16) & 1u);
            WiT[(size_t)k * CD + d] = (unsigned short)(r >> 16);
        }
    }
}

// ---------------- K1: fused scores + softmax pieces + num ----------------
// BM=128, BK=64, 8 chunks. sA 128x64 bf16 swizzled (16 KB, single buf,
// reg-prefetched); sB 256x64 bf16 glds-staged (32 KB, single buf). 48 KB LDS,
// 2 blocks/CU (reg-limited). grid (16, 32).
__global__ __launch_bounds__(256, 2) void scores_fused_kernel(
        const float* __restrict__ vI, const unsigned short* __restrict__ WiT,
        const float* __restrict__ vQp, const float* __restrict__ Wp,
        float* __restrict__ numP, float* __restrict__ Zp, float* __restrict__ mP)
{
    constexpr int BM = 128;
    __shared__ __align__(16) unsigned short sA[BM * 64];    // 16 KB
    __shared__ __align__(16) unsigned short sB[CK * 64];    // 32 KB
    float* sred = (float*)sB;          // [4][128]  (aliased after K-loop)
    float* sS   = ((float*)sB) + 512;  // [128] scores
    float* sW   = ((float*)sB) + 640;  // [128] exp weights
    float* sacc = ((float*)sB) + 1024; // [4][512] num partials

    const int tid  = threadIdx.x;
    const int b    = blockIdx.y;
    const int n0   = blockIdx.x * BM;
    const int wave = tid >> 6;
    const int lane = tid & 63;
    const int col  = lane & 15;
    const int quad = lane >> 4;
    const float* vIb = vI + ((size_t)b * CN + n0) * CD;

    // glds B source offsets (xor-swizzled col groups, lane-linear LDS dest).
    // Resulting LDS addr of (row R, col-group c): R*64 + ((c^(R&7))<<3) ushorts.
    int gBoff[8];
    #pragma unroll
    for (int t = 0; t < 8; ++t) {
        int row = wave * 64 + t * 8 + (lane >> 3);
        int c   = (lane & 7) ^ (row & 7);
        gBoff[t] = row * CD + c * 8;
    }

    // A stage slots: q = i*256+tid, r=q>>3 (0..127), c=q&7 (16B chunk)
    const int arow = tid >> 3;          // +i*32
    const int acol = tid & 7;

    // ---- prologue: B(0) glds; rA(0) load; stage sA(0) ----
    #pragma unroll
    for (int t = 0; t < 8; ++t)
        glds16(WiT + gBoff[t], (unsigned short*)sB + (wave * 8 + t) * 512 + lane * 8);

    float4 rA[8];
    #pragma unroll
    for (int i = 0; i < 4; ++i) {
        const float* src = vIb + (size_t)(arow + i * 32) * CD + acol * 8;
        rA[2 * i]     = *reinterpret_cast<const float4*>(src);
        rA[2 * i + 1] = *reinterpret_cast<const float4*>(src + 4);
    }
    #pragma unroll
    for (int i = 0; i < 4; ++i) {
        int r = arow + i * 32;
        uint4 p;
        p.x = pk2bf(rA[2 * i].x,     rA[2 * i].y);
        p.y = pk2bf(rA[2 * i].z,     rA[2 * i].w);
        p.z = pk2bf(rA[2 * i + 1].x, rA[2 * i + 1].y);
        p.w = pk2bf(rA[2 * i + 1].z, rA[2 * i + 1].w);
        *reinterpret_cast<uint4*>(&sA[r * 64 + ((acol ^ (r & 7)) << 3)]) = p;
    }

    f32x4 acc[8][4];
    #pragma unroll
    for (int mt = 0; mt < 8; ++mt)
        #pragma unroll
        for (int kt = 0; kt < 4; ++kt)
            acc[mt][kt] = (f32x4){0.f, 0.f, 0.f, 0.f};

    __syncthreads();   // sA(0) written, B(0) landed

    // ---- K loop: 8 chunks of 64 d ----
    #pragma unroll
    for (int ch = 0; ch < 8; ++ch) {
        // issue next A loads first: in flight across the whole compute phase
        if (ch < 7) {
            const int d0n = (ch + 1) * 64;
            #pragma unroll
            for (int i = 0; i < 4; ++i) {
                const float* src = vIb + (size_t)(arow + i * 32) * CD + d0n + acol * 8;
                rA[2 * i]     = *reinterpret_cast<const float4*>(src);
                rA[2 * i + 1] = *reinterpret_cast<const float4*>(src + 4);
            }
        }
        #pragma unroll
        for (int s = 0; s < 2; ++s) {
            bf16x8 af[8], bfr[4];
            #pragma unroll
            for (int mt = 0; mt < 8; ++mt) {
                int row = mt * 16 + col;
                af[mt] = *reinterpret_cast<const bf16x8*>(
                    &sA[row * 64 + ((((s << 2) + quad) ^ (col & 7)) << 3)]);
            }
            #pragma unroll
            for (int kt = 0; kt < 4; ++kt) {
                int R = wave * 64 + kt * 16 + col;
                bfr[kt] = *reinterpret_cast<const bf16x8*>(
                    (unsigned short*)sB + R * 64 + ((((s << 2) + quad) ^ (col & 7)) << 3));
            }
            #pragma unroll
            for (int mt = 0; mt < 8; ++mt)
                #pragma unroll
                for (int kt = 0; kt < 4; ++kt)
                    acc[mt][kt] = __builtin_amdgcn_mfma_f32_16x16x32_bf16(
                        af[mt], bfr[kt], acc[mt][kt], 0, 0, 0);
        }
        __syncthreads();   // compute(ch) done; drains rA(ch+1) loads
        if (ch < 7) {
            // stage sA(ch+1) from registers
            #pragma unroll
            for (int i = 0; i < 4; ++i) {
                int r = arow + i * 32;
                uint4 p;
                p.x = pk2bf(rA[2 * i].x,     rA[2 * i].y);
                p.y = pk2bf(rA[2 * i].z,     rA[2 * i].w);
                p.z = pk2bf(rA[2 * i + 1].x, rA[2 * i + 1].y);
                p.w = pk2bf(rA[2 * i + 1].z, rA[2 * i + 1].w);
                *reinterpret_cast<uint4*>(&sA[r * 64 + ((acol ^ (r & 7)) << 3)]) = p;
            }
            // glds B(ch+1): sB reads finished at the barrier above
            const int d0n = (ch + 1) * 64;
            #pragma unroll
            for (int t = 0; t < 8; ++t)
                glds16(WiT + gBoff[t] + d0n,
                       (unsigned short*)sB + (wave * 8 + t) * 512 + lane * 8);
            __syncthreads();   // sA write + glds visible
        }
    }

    // ---- epilogue 1: per-row scores ----
    float vq[4], wp[4];
    #pragma unroll
    for (int kt = 0; kt < 4; ++kt) {
        int k = wave * 64 + kt * 16 + col;
        vq[kt] = vQp[b * CK + k];
        wp[kt] = Wp[k];
    }
    float sp[8][4];
    #pragma unroll
    for (int mt = 0; mt < 8; ++mt)
        #pragma unroll
        for (int r = 0; r < 4; ++r) {
            float s = 0.f;
            #pragma unroll
            for (int kt = 0; kt < 4; ++kt) {
                float v = acc[mt][kt][r] + vq[kt];
                v = v > 0.f ? v : 0.01f * v;     // leaky relu
                s += v * wp[kt];
            }
            sp[mt][r] = s;
        }
    #pragma unroll
    for (int off = 1; off < 16; off <<= 1)
        #pragma unroll
        for (int mt = 0; mt < 8; ++mt)
            #pragma unroll
            for (int r = 0; r < 4; ++r)
                sp[mt][r] += __shfl_xor(sp[mt][r], off);

    __syncthreads();   // final K-loop sB reads done -> safe to alias
    if (col == 0) {
        #pragma unroll
        for (int mt = 0; mt < 8; ++mt)
            #pragma unroll
            for (int r = 0; r < 4; ++r)
                sred[wave * 128 + mt * 16 + quad * 4 + r] = sp[mt][r];
    }
    __syncthreads();
    if (tid < BM)
        sS[tid] = sred[tid] + sred[128 + tid] + sred[256 + tid] + sred[384 + tid];
    __syncthreads();

    // ---- epilogue 2: block-local softmax pieces ----
    float m = -1e30f;
    #pragma unroll 8
    for (int i = 0; i < BM; ++i) m = fmaxf(m, sS[i]);
    if (tid < BM) sW[tid] = __expf(sS[tid] - m);
    __syncthreads();
    const int pidx = b * 16 + blockIdx.x;
    if (tid < 64) {
        float z0 = sW[tid], z1 = sW[tid + 64];
        float z = z0 + z1;
        #pragma unroll
        for (int off = 32; off > 0; off >>= 1) z += __shfl_xor(z, off);
        if (tid == 0) { Zp[pidx] = z; mP[pidx] = m; }
    }

    // ---- epilogue 3: num[d] = sum_n w_n * vI[n][d] (fp32, L2/L3-hot re-read) ----
    float a8[8] = {0.f, 0.f, 0.f, 0.f, 0.f, 0.f, 0.f, 0.f};
    const float* vrow = vIb + (size_t)(wave * 32) * CD + lane * 8;
    #pragma unroll 4
    for (int i = 0; i < 32; ++i) {
        float w = sW[wave * 32 + i];
        float4 u0 = *reinterpret_cast<const float4*>(vrow);
        float4 u1 = *reinterpret_cast<const float4*>(vrow + 4);
        a8[0] += w * u0.x; a8[1] += w * u0.y; a8[2] += w * u0.z; a8[3] += w * u0.w;
        a8[4] += w * u1.x; a8[5] += w * u1.y; a8[6] += w * u1.z; a8[7] += w * u1.w;
        vrow += CD;
    }
    *reinterpret_cast<float4*>(&sacc[wave * 512 + lane * 8])     = (float4){a8[0], a8[1], a8[2], a8[3]};
    *reinterpret_cast<float4*>(&sacc[wave * 512 + lane * 8 + 4]) = (float4){a8[4], a8[5], a8[6], a8[7]};
    __syncthreads();
    #pragma unroll
    for (int c = tid; c < CD; c += 256)
        numP[(size_t)pidx * CD + c] =
            sacc[c] + sacc[512 + c] + sacc[1024 + c] + sacc[1536 + c];
}

// ---------------- K2: combine 16 partials -> vbar; out = vbar@Wi + vQp ----------------
__global__ __launch_bounds__(256) void finalize_kernel(
        const float* __restrict__ numP, const float* __restrict__ Zp,
        const float* __restrict__ mP, const float* __restrict__ Wi,
        const float* __restrict__ vQp, float* __restrict__ out)
{
    const int b = blockIdx.x, tid = threadIdx.x;
    __shared__ float sv[CD];
    float M = -1e30f;
    #pragma unroll
    for (int j = 0; j < 16; ++j) M = fmaxf(M, mP[b * 16 + j]);
    float w[16]; float Zt = 0.f;
    #pragma unroll
    for (int j = 0; j < 16; ++j) {
        w[j] = __expf(mP[b * 16 + j] - M);
        Zt += w[j] * Zp[b * 16 + j];
    }
    const float inv = 1.f / Zt;
    for (int c = tid; c < CD; c += 256) {
        float s = 0.f;
        #pragma unroll
        for (int j = 0; j < 16; ++j) s += w[j] * numP[(size_t)(b * 16 + j) * CD + c];
        sv[c] = s * inv;
    }
    __syncthreads();
    float acc = vQp[b * CK + tid];
    #pragma unroll 8
    for (int d = 0; d < CD; ++d) acc += sv[d] * Wi[d * CK + tid];
    out[b * CK + tid] = acc;
}

extern "C" void kernel_launch(void* const* d_in, const int* in_sizes, int n_in,
                              void* d_out, int out_size, void* d_ws, size_t ws_size,
                              hipStream_t stream)
{
    const float* vI = (const float*)d_in[0];   // [B,N,D]
    const float* vQ = (const float*)d_in[1];   // [B,D]
    const float* Wi = (const float*)d_in[2];   // [D,K]
    const float* Wq = (const float*)d_in[3];   // [D,K]
    const float* bq = (const float*)d_in[4];   // [K]
    const float* Wp = (const float*)d_in[5];   // [K,1]
    // d_in[6] = bp: softmax-invariant, unused
    float* out = (float*)d_out;                // [B,K]

    char* ws = (char*)d_ws;
    float*          vQp  = (float*)(ws);                         //  32 KB
    unsigned short* WiT  = (unsigned short*)(ws + 32768);        // 256 KB
    float*          numP = (float*)(ws + 294912);                //   1 MB (512x512)
    float*          Zp   = (float*)(ws + 294912 + 2097152);      //   4 KB
    float*          mP   = (float*)(ws + 294912 + 2097152 + 4096);

    prep_kernel        <<<CB + CK, 256, 0, stream>>>(vQ, Wq, bq, Wi, vQp, WiT);
    scores_fused_kernel<<<dim3(CN / 128, CB), 256, 0, stream>>>(vI, WiT, vQp, Wp,
                                                                numP, Zp, mP);
    finalize_kernel    <<<CB, 256, 0, stream>>>(numP, Zp, mP, Wi, vQp, out);
}